// Round 4
// baseline (4312.513 us; speedup 1.0000x reference)
//
#include <hip/hip_runtime.h>
#include <math.h>

#define BT 256
#define LT 256
#define KT 128
#define HT 256
#define LOSS_IDX ((size_t)BT*LT*KT)
#define PRED_IDX (LOSS_IDX + 1)
#define LDP 1280   // P row: [gammah 256 | alpha 128 | gipre 768 | zpre 128] f16
#define GH0 0
#define AL0 256
#define GI0 384
#define ZP0 1152

typedef _Float16 h2 __attribute__((ext_vector_type(2)));
typedef _Float16 f16x8 __attribute__((ext_vector_type(8)));
typedef float f32x4 __attribute__((ext_vector_type(4)));

__device__ __forceinline__ float fd2(h2 a, h2 b, float c){
#if __has_builtin(__builtin_amdgcn_fdot2)
  return __builtin_amdgcn_fdot2(a, b, c, false);
#else
  return c + (float)a[0]*(float)b[0] + (float)a[1]*(float)b[1];
#endif
}
__device__ __forceinline__ float dot8(f16x8 w, f16x8 a, float acc){
  acc = fd2(__builtin_shufflevector(w,w,0,1), __builtin_shufflevector(a,a,0,1), acc);
  acc = fd2(__builtin_shufflevector(w,w,2,3), __builtin_shufflevector(a,a,2,3), acc);
  acc = fd2(__builtin_shufflevector(w,w,4,5), __builtin_shufflevector(a,a,4,5), acc);
  acc = fd2(__builtin_shufflevector(w,w,6,7), __builtin_shufflevector(a,a,6,7), acc);
  return acc;
}
__device__ __forceinline__ float sigf(float v){ return 1.0f/(1.0f + __expf(-v)); }
__device__ __forceinline__ float tanh_fast(float v){
  float a = fminf(fabsf(v), 15.0f);
  float e2 = __expf(2.0f*a);
  float r = (e2 - 1.0f)/(e2 + 1.0f);
  return copysignf(r, v);
}
__device__ __forceinline__ float f16bits(unsigned u, int hi){
  union { unsigned short s; _Float16 h; } c;
  c.s = (unsigned short)(hi ? (u >> 16) : (u & 0xffff));
  return (float)c.h;
}

// ---------- packing kernels ----------
__global__ void pack_cast(const float* __restrict__ src, _Float16* __restrict__ dst,
                          int J, int Kd, int diag, int total){
  int idx = blockIdx.x*256 + threadIdx.x;
  if (idx >= total) return;
  float v = src[idx];
  if (diag && (idx / Kd) == (idx % Kd)) v = 0.0f;
  dst[idx] = (_Float16)v;
}
__global__ void pack_rowchunks(const float* __restrict__ src, _Float16* __restrict__ dst,
                               int J, int K, int total){
  int idx = blockIdx.x*256 + threadIdx.x;
  if (idx >= total) return;
  int j = idx % J, c = idx / J;
  #pragma unroll
  for (int e = 0; e < 8; ++e)
    dst[(size_t)idx*8 + e] = (_Float16)src[(size_t)j*K + c*8 + e];
}
__global__ void pack_col(const float* __restrict__ src, _Float16* __restrict__ dst,
                         int J, int Kc, int ld, int diag, int total){
  int idx = blockIdx.x*256 + threadIdx.x;
  if (idx >= total) return;
  int j = idx % J, k = idx / J;
  float v = src[(size_t)j*ld + k];
  if (diag && j == k) v = 0.0f;
  dst[idx] = (_Float16)v;
}

// ---------- scan: deltas + GEMM inputs ----------
__global__ __launch_bounds__(128) void scan_kernel(
    const float* __restrict__ x, const float* __restrict__ mask, const float* __restrict__ ts,
    const float* __restrict__ W_gx, const float* __restrict__ b_gx,
    const int* __restrict__ record_num,
    _Float16* __restrict__ deltas, _Float16* __restrict__ Agx, _Float16* __restrict__ U)
{
  int b = blockIdx.x, k = threadIdx.x;
  int rn = record_num[b];
  float gxd = W_gx[(size_t)k*KT + k];
  float bgx = b_gx[k];
  float d = 1.0f, tsp = 0.0f;
  for (int t0 = 0; t0 < LT; t0 += 8){
    float xv[8], mv[8], tsv[8];
    #pragma unroll
    for (int u = 0; u < 8; ++u){
      size_t off = ((size_t)b*LT + t0 + u)*KT + k;
      xv[u] = x[off]; mv[u] = mask[off];
      tsv[u] = ts[(size_t)b*LT + t0 + u];
    }
    #pragma unroll
    for (int u = 0; u < 8; ++u){
      int t = t0 + u;
      if (t > 0){
        float gap = fabsf(tsv[u] - (u ? tsv[u-1] : tsp));
        d = gap + (1.0f - mv[u])*d;
      }
      float e = (t < rn) ? 1.0f : 0.0f;
      float dev = d * e;
      size_t row = (size_t)b*LT + t;
      deltas[row*KT + k] = (_Float16)dev;
      float gx = __expf(-fmaxf(fmaf(dev, gxd, bgx), 0.0f));
      Agx[row*2*KT + k]      = (_Float16)gx;
      Agx[row*2*KT + KT + k] = (_Float16)mv[u];
      U[row*2*KT + k]        = (_Float16)(mv[u]*xv[u]);
      U[row*2*KT + KT + k]   = (_Float16)mv[u];
    }
    tsp = tsv[7];
  }
}

__global__ void msum_kernel(const float* __restrict__ mask, float* __restrict__ msumInv){
  __shared__ float red[256];
  int t = blockIdx.x;
  float acc = 0.0f;
  for (int i = threadIdx.x; i < BT*KT; i += 256){
    int b = i >> 7, k = i & 127;
    acc += mask[((size_t)b*LT + t)*KT + k];
  }
  red[threadIdx.x] = acc; __syncthreads();
  for (int s = 128; s > 0; s >>= 1){
    if (threadIdx.x < s) red[threadIdx.x] += red[threadIdx.x + s];
    __syncthreads();
  }
  if (threadIdx.x == 0) msumInv[t] = 1.0f/(red[0] + 1e-5f);
}

// ---------- MFMA GEMM ----------
__global__ __launch_bounds__(256) void gemm_f16(
    const _Float16* __restrict__ A, long ldA, int K,
    const _Float16* __restrict__ B, long ldB,
    _Float16* __restrict__ C, long colofs,
    const float* __restrict__ bias, int op)
{
  const int w = threadIdx.x >> 6, lane = threadIdx.x & 63;
  const int ml = lane & 15, quad = lane >> 4;
  const long m0 = (long)blockIdx.x*64 + w*16;
  const long nb0 = (long)blockIdx.y*64;
  f32x4 acc[4] = {{0,0,0,0},{0,0,0,0},{0,0,0,0},{0,0,0,0}};
  for (int kc = 0; kc < K; kc += 32){
    f16x8 a = *(const f16x8*)(A + (m0 + ml)*ldA + kc + quad*8);
    #pragma unroll
    for (int nt = 0; nt < 4; ++nt){
      f16x8 bfr = *(const f16x8*)(B + (nb0 + nt*16 + ml)*ldB + kc + quad*8);
      acc[nt] = __builtin_amdgcn_mfma_f32_16x16x32_f16(a, bfr, acc[nt], 0, 0, 0);
    }
  }
  #pragma unroll
  for (int nt = 0; nt < 4; ++nt){
    long col = nb0 + nt*16 + ml;
    float bv = (op >= 1) ? bias[col] : 0.0f;
    #pragma unroll
    for (int r = 0; r < 4; ++r){
      float v = acc[nt][r];
      if (op >= 1) v += bv;
      if (op == 2) v = __expf(-fmaxf(v, 0.0f));
      long row = m0 + quad*4 + r;
      C[row*LDP + colofs + col] = (_Float16)v;
    }
  }
}

// ---------- sequential recurrence: 1 block per batch, 3 barriers/step ----------
// Phase A  : prefetch-issue row t+1; xh dot + missing-list (tid<128)
// Phase CD : sparse z/ch/losses/imputation/v5 (tid<128)  ||  full gh dot
//            (tid>=128, W_hh L2 stream overlapped with z-chain)  ||  stage
//            prefetched buffers
// Phase G  : sparse gi (3 comps/thread, tid<256, gi stays in registers),
//            gates, h update in REGISTER, hs(t+1)=h*gamma(t+1) -> hsh
// All cross-barrier state is scalar registers (R0-proven; no arrays -> no spill).
#define NT 768

struct __align__(16) SeqS {
  f16x8 whist_l[32*128];        // 64 KB, [c*128 + j]
  _Float16 wfc_l[128*128];      // 32 KB, [k*128 + j]
  alignas(16) _Float16 hsh[HT];
  float gh[3*HT];
  float xh[KT];
  float v3[KT], v5[KT];
  int lidx[136];
  int posk[KT];
  int cnt[2];
  unsigned pb[2][LDP/2];
  float xb[2][KT], mb[2][KT];
  float bhist[KT], bfeat[KT];
  float bhh[3*HT];
  float wout[HT];
  float minv[LT];
  float red[NT/64];
};

__global__ __launch_bounds__(NT, 1) void rits_seq(
    const float* __restrict__ x, const float* __restrict__ mask,
    const int* __restrict__ record_num, const float* __restrict__ msumInv,
    const _Float16* __restrict__ P,
    const f16x8* __restrict__ Whh_p, const f16x8* __restrict__ Whist_p,
    const _Float16* __restrict__ Wfc, const _Float16* __restrict__ Wihc,
    const float* __restrict__ b_hist, const float* __restrict__ b_feat,
    const float* __restrict__ b_hh,
    const float* __restrict__ W_out, const float* __restrict__ b_out,
    float* __restrict__ out)
{
  __shared__ SeqS s;
  const int tid = threadIdx.x;
  const int b = blockIdx.x;
  const int rn = record_num[b];
  const unsigned* __restrict__ Pd = (const unsigned*)P + (size_t)b*LT*(LDP/2);

  // ---- init ----
  for (int i = tid; i < 32*128; i += NT) s.whist_l[i] = Whist_p[i];
  for (int i = tid; i < 128*128/2; i += NT)
    ((unsigned*)s.wfc_l)[i] = ((const unsigned*)Wfc)[i];
  if (tid < KT){ s.bhist[tid] = b_hist[tid]; s.bfeat[tid] = b_feat[tid]; s.v3[tid] = 0.0f; }
  if (tid < 3*HT) s.bhh[tid] = b_hh[tid];
  if (tid < 136) s.lidx[tid] = 0;
  if (tid < HT) s.hsh[tid] = (_Float16)0.0f;
  if (tid == 0){ s.cnt[0] = 0; s.cnt[1] = 0; }
  if (tid >= 256 && tid < 512) s.wout[tid - 256] = W_out[tid - 256];
  if (tid >= 512 && tid < 512 + LT) s.minv[tid - 512] = msumInv[tid - 512];
  // stage t=0 streams into buffer 0
  if (tid < LDP/2) s.pb[0][tid] = Pd[tid];
  else if (tid < LDP/2 + KT){
    int k = tid - LDP/2;
    s.xb[0][k] = x[((size_t)b*LT)*KT + k];
    s.mb[0][k] = mask[((size_t)b*LT)*KT + k];
  }
  __syncthreads();

  float loss = 0.0f;
  float h_reg = 0.0f;   // tid<256: GRU hidden state (register-resident)
  float hs_r = 0.0f;    // tid<256: decayed h for current step t

  for (int t = 0; t < LT; ++t){
    const int cur = t & 1, nxt = cur ^ 1;

    // ================= phase A =================
    unsigned pr0 = 0; float prx = 0.0f, prm = 0.0f;
    if (t < LT - 1 && tid >= 128){
      pr0 = Pd[(size_t)(t+1)*(LDP/2) + (tid - 128)];
      if (tid < 256){
        int k = tid - 128;
        size_t o = ((size_t)b*LT + t + 1)*KT + k;
        prx = x[o]; prm = mask[o];
      }
    }
    if (tid == 0) s.cnt[nxt] = 0;
    if (tid < KT){
      const f16x8* hp = (const f16x8*)s.hsh;
      float b0 = 0.0f, b1 = 0.0f, b2 = 0.0f, b3 = 0.0f;
      #pragma unroll 8
      for (int c = 0; c < 32; c += 4){
        b0 = dot8(s.whist_l[c*128 + tid],     hp[c],   b0);
        b1 = dot8(s.whist_l[(c+1)*128 + tid], hp[c+1], b1);
        b2 = dot8(s.whist_l[(c+2)*128 + tid], hp[c+2], b2);
        b3 = dot8(s.whist_l[(c+3)*128 + tid], hp[c+3], b3);
      }
      float xh = (b0 + b1) + (b2 + b3) + s.bhist[tid];
      s.xh[tid] = xh;
      float mv = s.mb[cur][tid];
      if (mv == 0.0f){
        int pp = atomicAdd(&s.cnt[cur], 1);
        s.lidx[pp] = tid; s.v3[pp] = xh; s.posk[tid] = pp;
      }
    }
    __syncthreads();

    // ================= phase CD =================
    const int c0 = s.cnt[cur];
    const int c4 = (c0 + 7) & ~7;
    if (tid >= 128){
      const f16x8* hp = (const f16x8*)s.hsh;
      {
        const int o = tid - 128;                 // gh outputs 0..639
        float a0 = 0.0f, a1 = 0.0f, a2 = 0.0f, a3 = 0.0f;
        #pragma unroll 8
        for (int c = 0; c < 32; c += 4){
          a0 = dot8(Whh_p[(size_t)c*768 + o],     hp[c],   a0);
          a1 = dot8(Whh_p[(size_t)(c+1)*768 + o], hp[c+1], a1);
          a2 = dot8(Whh_p[(size_t)(c+2)*768 + o], hp[c+2], a2);
          a3 = dot8(Whh_p[(size_t)(c+3)*768 + o], hp[c+3], a3);
        }
        s.gh[o] = (a0 + a1) + (a2 + a3);
      }
      if (tid >= 256 && tid < 384){
        const int o = tid + 384;                 // gh outputs 640..767
        float a0 = 0.0f, a1 = 0.0f, a2 = 0.0f, a3 = 0.0f;
        #pragma unroll 8
        for (int c = 0; c < 32; c += 4){
          a0 = dot8(Whh_p[(size_t)c*768 + o],     hp[c],   a0);
          a1 = dot8(Whh_p[(size_t)(c+1)*768 + o], hp[c+1], a1);
          a2 = dot8(Whh_p[(size_t)(c+2)*768 + o], hp[c+2], a2);
          a3 = dot8(Whh_p[(size_t)(c+3)*768 + o], hp[c+3], a3);
        }
        s.gh[o] = (a0 + a1) + (a2 + a3);
      }
      // stage prefetched next-step buffers (after dots: loads have landed)
      if (t < LT - 1){
        s.pb[nxt][tid - 128] = pr0;
        if (tid < 256){
          int k = tid - 128;
          s.xb[nxt][k] = prx; s.mb[nxt][k] = prm;
        }
      }
    } else {
      const int j = tid;
      float z0 = 0.0f, z1 = 0.0f;
      for (int i = 0; i < c4; i += 2){           // v3 zero-padded to c4
        z0 += s.v3[i]   * (float)s.wfc_l[s.lidx[i]*128 + j];
        z1 += s.v3[i+1] * (float)s.wfc_l[s.lidx[i+1]*128 + j];
      }
      float z  = f16bits(s.pb[cur][ZP0/2 + (j >> 1)], j & 1) + s.bfeat[j] + z0 + z1;
      float al = f16bits(s.pb[cur][AL0/2 + (j >> 1)], j & 1);
      float xh = s.xh[j];
      float mv = s.mb[cur][j], xv = s.xb[cur][j];
      float e  = (t < rn) ? 1.0f : 0.0f;
      float inv = s.minv[t];
      float ch = al*z + (1.0f - al)*xh;
      loss += (fabsf(xv - xh) + (fabsf(xv - z) + fabsf(xv - ch))*e) * mv * inv;
      float cc = mv*xv + (1.0f - mv)*ch;
      out[((size_t)b*LT + t)*KT + j] = cc * e;
      if (j >= c0) s.v5[j] = 0.0f;               // zero-pad v5 to c4
      if (mv == 0.0f) s.v5[s.posk[j]] = ch;
    }
    __syncthreads();

    // ================= phase G =================
    if (tid < HT){
      const int j = tid;
      float gr = f16bits(s.pb[cur][GI0/2        + (j >> 1)], j & 1);
      float gz = f16bits(s.pb[cur][(GI0+HT)/2   + (j >> 1)], j & 1);
      float gg = f16bits(s.pb[cur][(GI0+2*HT)/2 + (j >> 1)], j & 1);
      for (int i = 0; i < c4; i += 8){
        #pragma unroll
        for (int u = 0; u < 8; ++u){
          int li = s.lidx[i + u];
          float v = s.v5[i + u];
          gr += v * (float)Wihc[(size_t)li*768 + j];
          gz += v * (float)Wihc[(size_t)li*768 + 256 + j];
          gg += v * (float)Wihc[(size_t)li*768 + 512 + j];
        }
      }
      float hr = s.gh[j]        + s.bhh[j];
      float hz = s.gh[HT + j]   + s.bhh[HT + j];
      float hg = s.gh[2*HT + j] + s.bhh[2*HT + j];
      float r  = sigf(gr + hr);
      float zg = sigf(gz + hz);
      float n  = tanh_fast(gg + r*hg);
      float hn = (1.0f - zg)*n + zg*hs_r;
      if (t < rn) h_reg = hn;
      if (t < LT - 1){
        float g = f16bits(s.pb[nxt][j >> 1], j & 1);   // gamma_h(t+1), GH0=0
        hs_r = h_reg * g;
        s.hsh[j] = (_Float16)hs_r;
      }
    } else if (tid < HT + KT){
      s.v3[tid - HT] = 0.0f;                     // re-zero v3 for next step
    }
    __syncthreads();
  }

  // ---- loss reduction ----
  #pragma unroll
  for (int off = 32; off; off >>= 1) loss += __shfl_down(loss, off);
  if ((tid & 63) == 0) s.red[tid >> 6] = loss;
  __syncthreads();
  if (tid == 0){
    float tot = 0.0f;
    #pragma unroll
    for (int w = 0; w < NT/64; ++w) tot += s.red[w];
    atomicAdd(&out[LOSS_IDX], tot);
  }

  // ---- prediction ----
  if (tid < HT) s.gh[tid] = h_reg * s.wout[tid];
  __syncthreads();
  for (int st2 = 128; st2 > 0; st2 >>= 1){
    if (tid < st2) s.gh[tid] += s.gh[tid + st2];
    __syncthreads();
  }
  if (tid == 0) out[PRED_IDX + b] = sigf(s.gh[0] + b_out[0]);
}

extern "C" void kernel_launch(void* const* d_in, const int* in_sizes, int n_in,
                              void* d_out, int out_size, void* d_ws, size_t ws_size,
                              hipStream_t stream){
  const float* x      = (const float*)d_in[0];
  const float* mask   = (const float*)d_in[1];
  const float* ts     = (const float*)d_in[2];
  const float* W_gh   = (const float*)d_in[3];
  const float* b_gh   = (const float*)d_in[4];
  const float* W_gx   = (const float*)d_in[5];
  const float* b_gx   = (const float*)d_in[6];
  const float* W_hist = (const float*)d_in[7];
  const float* b_hist = (const float*)d_in[8];
  const float* W_feat = (const float*)d_in[9];
  const float* b_feat = (const float*)d_in[10];
  const float* W_comb = (const float*)d_in[11];
  const float* b_comb = (const float*)d_in[12];
  const float* W_ih   = (const float*)d_in[13];
  const float* W_hh   = (const float*)d_in[14];
  const float* b_ih   = (const float*)d_in[15];
  const float* b_hh   = (const float*)d_in[16];
  const float* W_out  = (const float*)d_in[17];
  const float* b_out  = (const float*)d_in[18];
  const int*   rn     = (const int*)d_in[19];
  float* out = (float*)d_out;
  char* ws = (char*)d_ws;

  size_t off = 0;
  auto alloc = [&](size_t bytes) -> char* {
    char* p = ws + off;
    off += (bytes + 255) & ~(size_t)255;
    return p;
  };
  _Float16* P      = (_Float16*)alloc((size_t)BT*LT*LDP*2);   // 167.8 MB
  _Float16* deltas = (_Float16*)alloc((size_t)BT*LT*KT*2);    // 16.8 MB
  _Float16* Agx    = (_Float16*)alloc((size_t)BT*LT*2*KT*2);  // 33.6 MB
  _Float16* U      = (_Float16*)alloc((size_t)BT*LT*2*KT*2);  // 33.6 MB
  _Float16* WghF   = (_Float16*)alloc(HT*KT*2);
  _Float16* WcombF = (_Float16*)alloc(KT*2*KT*2);
  _Float16* WihF   = (_Float16*)alloc(3*HT*2*KT*2);
  _Float16* WfeatF = (_Float16*)alloc(KT*KT*2);
  _Float16* Whh_p  = (_Float16*)alloc(3*HT*HT*2);
  _Float16* Whist_p= (_Float16*)alloc(KT*HT*2);
  _Float16* Wfc    = (_Float16*)alloc(KT*KT*2);
  _Float16* Wihc   = (_Float16*)alloc(KT*3*HT*2);
  float* msumInv   = (float*)alloc(LT*4);

  auto grid1 = [](int n){ return dim3((n + 255)/256); };
  pack_cast<<<grid1(HT*KT), 256, 0, stream>>>(W_gh, WghF, HT, KT, 0, HT*KT);
  pack_cast<<<grid1(KT*2*KT), 256, 0, stream>>>(W_comb, WcombF, KT, 2*KT, 0, KT*2*KT);
  pack_cast<<<grid1(3*HT*2*KT), 256, 0, stream>>>(W_ih, WihF, 3*HT, 2*KT, 0, 3*HT*2*KT);
  pack_cast<<<grid1(KT*KT), 256, 0, stream>>>(W_feat, WfeatF, KT, KT, 1, KT*KT);
  pack_rowchunks<<<grid1(3*HT*(HT/8)), 256, 0, stream>>>(W_hh, Whh_p, 3*HT, HT, 3*HT*(HT/8));
  pack_rowchunks<<<grid1(KT*(HT/8)), 256, 0, stream>>>(W_hist, Whist_p, KT, HT, KT*(HT/8));
  pack_col<<<grid1(KT*KT), 256, 0, stream>>>(W_feat, Wfc, KT, KT, KT, 1, KT*KT);
  pack_col<<<grid1(768*KT), 256, 0, stream>>>(W_ih, Wihc, 3*HT, KT, 2*KT, 0, 3*HT*KT);

  scan_kernel<<<dim3(BT), dim3(KT), 0, stream>>>(x, mask, ts, W_gx, b_gx, rn, deltas, Agx, U);
  msum_kernel<<<dim3(LT), dim3(256), 0, stream>>>(mask, msumInv);

  const int MR = BT*LT;
  gemm_f16<<<dim3(MR/64, HT/64), 256, 0, stream>>>(deltas, KT, KT, WghF, KT, P, GH0, b_gh, 2);
  gemm_f16<<<dim3(MR/64, KT/64), 256, 0, stream>>>(Agx, 2*KT, 2*KT, WcombF, 2*KT, P, AL0, b_comb, 1);
  gemm_f16<<<dim3(MR/64, 3*HT/64), 256, 0, stream>>>(U, 2*KT, 2*KT, WihF, 2*KT, P, GI0, b_ih, 1);
  gemm_f16<<<dim3(MR/64, KT/64), 256, 0, stream>>>(U, 2*KT, KT, WfeatF, KT, P, ZP0, (const float*)nullptr, 0);

  hipMemsetAsync((void*)(out + LOSS_IDX), 0, sizeof(float), stream);

  rits_seq<<<dim3(BT), dim3(NT), 0, stream>>>(x, mask, rn, msumInv, P,
      (const f16x8*)Whh_p, (const f16x8*)Whist_p, Wfc, Wihc,
      b_hist, b_feat, b_hh, W_out, b_out, out);
}

// Round 5
// 2441.686 us; speedup vs baseline: 1.7662x; 1.7662x over previous
//
#include <hip/hip_runtime.h>
#include <math.h>

#define BT 256
#define LT 256
#define KT 128
#define HT 256
#define LOSS_IDX ((size_t)BT*LT*KT)
#define PRED_IDX (LOSS_IDX + 1)
#define LDP 1280   // P row: [gammah 256 | alpha 128 | gipre 768 | zpre 128] f16
#define GH0 0
#define AL0 256
#define GI0 384
#define ZP0 1152

typedef _Float16 h2 __attribute__((ext_vector_type(2)));
typedef _Float16 f16x8 __attribute__((ext_vector_type(8)));
typedef float f32x4 __attribute__((ext_vector_type(4)));

__device__ __forceinline__ float fd2(h2 a, h2 b, float c){
#if __has_builtin(__builtin_amdgcn_fdot2)
  return __builtin_amdgcn_fdot2(a, b, c, false);
#else
  return c + (float)a[0]*(float)b[0] + (float)a[1]*(float)b[1];
#endif
}
__device__ __forceinline__ float dot8(f16x8 w, f16x8 a, float acc){
  acc = fd2(__builtin_shufflevector(w,w,0,1), __builtin_shufflevector(a,a,0,1), acc);
  acc = fd2(__builtin_shufflevector(w,w,2,3), __builtin_shufflevector(a,a,2,3), acc);
  acc = fd2(__builtin_shufflevector(w,w,4,5), __builtin_shufflevector(a,a,4,5), acc);
  acc = fd2(__builtin_shufflevector(w,w,6,7), __builtin_shufflevector(a,a,6,7), acc);
  return acc;
}
__device__ __forceinline__ float sigf(float v){ return 1.0f/(1.0f + __expf(-v)); }
__device__ __forceinline__ float tanh_fast(float v){
  float a = fminf(fabsf(v), 15.0f);
  float e2 = __expf(2.0f*a);
  float r = (e2 - 1.0f)/(e2 + 1.0f);
  return copysignf(r, v);
}
__device__ __forceinline__ float f16bits(unsigned u, int hi){
  union { unsigned short s; _Float16 h; } c;
  c.s = (unsigned short)(hi ? (u >> 16) : (u & 0xffff));
  return (float)c.h;
}

// ---------- packing kernels ----------
__global__ void pack_cast(const float* __restrict__ src, _Float16* __restrict__ dst,
                          int J, int Kd, int diag, int total){
  int idx = blockIdx.x*256 + threadIdx.x;
  if (idx >= total) return;
  float v = src[idx];
  if (diag && (idx / Kd) == (idx % Kd)) v = 0.0f;
  dst[idx] = (_Float16)v;
}
__global__ void pack_rowchunks(const float* __restrict__ src, _Float16* __restrict__ dst,
                               int J, int K, int total){
  int idx = blockIdx.x*256 + threadIdx.x;
  if (idx >= total) return;
  int j = idx % J, c = idx / J;
  #pragma unroll
  for (int e = 0; e < 8; ++e)
    dst[(size_t)idx*8 + e] = (_Float16)src[(size_t)j*K + c*8 + e];
}
__global__ void pack_col(const float* __restrict__ src, _Float16* __restrict__ dst,
                         int J, int Kc, int ld, int diag, int total){
  int idx = blockIdx.x*256 + threadIdx.x;
  if (idx >= total) return;
  int j = idx % J, k = idx / J;
  float v = src[(size_t)j*ld + k];
  if (diag && j == k) v = 0.0f;
  dst[idx] = (_Float16)v;
}

// ---------- scan: deltas + GEMM inputs ----------
__global__ __launch_bounds__(128) void scan_kernel(
    const float* __restrict__ x, const float* __restrict__ mask, const float* __restrict__ ts,
    const float* __restrict__ W_gx, const float* __restrict__ b_gx,
    const int* __restrict__ record_num,
    _Float16* __restrict__ deltas, _Float16* __restrict__ Agx, _Float16* __restrict__ U)
{
  int b = blockIdx.x, k = threadIdx.x;
  int rn = record_num[b];
  float gxd = W_gx[(size_t)k*KT + k];
  float bgx = b_gx[k];
  float d = 1.0f, tsp = 0.0f;
  for (int t0 = 0; t0 < LT; t0 += 8){
    float xv[8], mv[8], tsv[8];
    #pragma unroll
    for (int u = 0; u < 8; ++u){
      size_t off = ((size_t)b*LT + t0 + u)*KT + k;
      xv[u] = x[off]; mv[u] = mask[off];
      tsv[u] = ts[(size_t)b*LT + t0 + u];
    }
    #pragma unroll
    for (int u = 0; u < 8; ++u){
      int t = t0 + u;
      if (t > 0){
        float gap = fabsf(tsv[u] - (u ? tsv[u-1] : tsp));
        d = gap + (1.0f - mv[u])*d;
      }
      float e = (t < rn) ? 1.0f : 0.0f;
      float dev = d * e;
      size_t row = (size_t)b*LT + t;
      deltas[row*KT + k] = (_Float16)dev;
      float gx = __expf(-fmaxf(fmaf(dev, gxd, bgx), 0.0f));
      Agx[row*2*KT + k]      = (_Float16)gx;
      Agx[row*2*KT + KT + k] = (_Float16)mv[u];
      U[row*2*KT + k]        = (_Float16)(mv[u]*xv[u]);
      U[row*2*KT + KT + k]   = (_Float16)mv[u];
    }
    tsp = tsv[7];
  }
}

__global__ void msum_kernel(const float* __restrict__ mask, float* __restrict__ msumInv){
  __shared__ float red[256];
  int t = blockIdx.x;
  float acc = 0.0f;
  for (int i = threadIdx.x; i < BT*KT; i += 256){
    int b = i >> 7, k = i & 127;
    acc += mask[((size_t)b*LT + t)*KT + k];
  }
  red[threadIdx.x] = acc; __syncthreads();
  for (int s = 128; s > 0; s >>= 1){
    if (threadIdx.x < s) red[threadIdx.x] += red[threadIdx.x + s];
    __syncthreads();
  }
  if (threadIdx.x == 0) msumInv[t] = 1.0f/(red[0] + 1e-5f);
}

// ---------- MFMA GEMM ----------
__global__ __launch_bounds__(256) void gemm_f16(
    const _Float16* __restrict__ A, long ldA, int K,
    const _Float16* __restrict__ B, long ldB,
    _Float16* __restrict__ C, long colofs,
    const float* __restrict__ bias, int op)
{
  const int w = threadIdx.x >> 6, lane = threadIdx.x & 63;
  const int ml = lane & 15, quad = lane >> 4;
  const long m0 = (long)blockIdx.x*64 + w*16;
  const long nb0 = (long)blockIdx.y*64;
  f32x4 acc[4] = {{0,0,0,0},{0,0,0,0},{0,0,0,0},{0,0,0,0}};
  for (int kc = 0; kc < K; kc += 32){
    f16x8 a = *(const f16x8*)(A + (m0 + ml)*ldA + kc + quad*8);
    #pragma unroll
    for (int nt = 0; nt < 4; ++nt){
      f16x8 bfr = *(const f16x8*)(B + (nb0 + nt*16 + ml)*ldB + kc + quad*8);
      acc[nt] = __builtin_amdgcn_mfma_f32_16x16x32_f16(a, bfr, acc[nt], 0, 0, 0);
    }
  }
  #pragma unroll
  for (int nt = 0; nt < 4; ++nt){
    long col = nb0 + nt*16 + ml;
    float bv = (op >= 1) ? bias[col] : 0.0f;
    #pragma unroll
    for (int r = 0; r < 4; ++r){
      float v = acc[nt][r];
      if (op >= 1) v += bv;
      if (op == 2) v = __expf(-fmaxf(v, 0.0f));
      long row = m0 + quad*4 + r;
      C[row*LDP + colofs + col] = (_Float16)v;
    }
  }
}

// ---------- sequential recurrence: 1 block per batch, 5 barriers/step ----------
// R0's proven 6-phase body with phase P1 deleted:
//  - h and hs live in scalar registers (tid<256), never round-trip LDS
//  - hs(t+1) is computed at the end of F using gam_pr (a per-thread copy of
//    the gamma_h dword loaded in A), and hsh is written there, so A starts
//    directly off F's barrier.
//  - cnt double-buffered; reset folded into A.
// All other phases (A/C/D/E/F) keep R0's exact code and thread mapping.
#define NT 768

struct __align__(16) SeqS {
  f16x8 whist_l[32*128];        // 64 KB, [c*128 + j]
  _Float16 wfc_l[128*128];      // 32 KB, [k*128 + j]
  alignas(16) _Float16 hsh[HT];
  float gh[3*HT];
  float gi[3*HT];
  float xh[KT];
  float part6[6][KT];
  float v3[KT], v5[KT];
  int lidx[136];
  int posk[KT];
  int cnt[2];
  unsigned pb[2][LDP/2];
  float xb[2][KT], mb[2][KT];
  float bhist[KT], bfeat[KT];
  float bhh[3*HT];
  float wout[HT];
  float minv[LT];
  float red[NT/64];
};

__global__ __launch_bounds__(NT, 1) void rits_seq(
    const float* __restrict__ x, const float* __restrict__ mask,
    const int* __restrict__ record_num, const float* __restrict__ msumInv,
    const _Float16* __restrict__ P,
    const f16x8* __restrict__ Whh_p, const f16x8* __restrict__ Whist_p,
    const _Float16* __restrict__ Wfc, const _Float16* __restrict__ Wihc,
    const float* __restrict__ b_hist, const float* __restrict__ b_feat,
    const float* __restrict__ b_hh,
    const float* __restrict__ W_out, const float* __restrict__ b_out,
    float* __restrict__ out)
{
  __shared__ SeqS s;
  const int tid = threadIdx.x;
  const int b = blockIdx.x;
  const int rn = record_num[b];
  const unsigned* __restrict__ Pd = (const unsigned*)P + (size_t)b*LT*(LDP/2);

  // ---- init: LDS-resident weights + constants ----
  for (int i = tid; i < 32*128; i += NT) s.whist_l[i] = Whist_p[i];
  for (int i = tid; i < 128*128/2; i += NT)
    ((unsigned*)s.wfc_l)[i] = ((const unsigned*)Wfc)[i];
  if (tid < HT) s.hsh[tid] = (_Float16)0.0f;
  if (tid < KT){ s.bhist[tid] = b_hist[tid]; s.bfeat[tid] = b_feat[tid]; }
  if (tid < 3*HT) s.bhh[tid] = b_hh[tid];
  if (tid < 136) s.lidx[tid] = 0;
  if (tid == 0){ s.cnt[0] = 0; s.cnt[1] = 0; }
  if (tid >= 256 && tid < 512) s.wout[tid - 256] = W_out[tid - 256];
  if (tid >= 512 && tid < 512 + LT) s.minv[tid - 512] = msumInv[tid - 512];
  // preload t=0 streams
  if (tid < LDP/2) s.pb[0][tid] = Pd[tid];
  else if (tid < LDP/2 + KT){
    int k = tid - LDP/2;
    s.xb[0][k] = x[((size_t)b*LT)*KT + k];
    s.mb[0][k] = mask[((size_t)b*LT)*KT + k];
  }
  __syncthreads();

  float loss = 0.0f;
  float h_reg = 0.0f;   // tid<256: GRU hidden state (register-resident)
  float hs_r = 0.0f;    // tid<256: decayed h for current step t

  for (int t = 0; t < LT; ++t){
    const int cur = t & 1, nxt = cur ^ 1;

    // ---- A: prefetch issue; gh (all 768, inline Whh);
    //         xh/loss1/list (tid<128, LDS Whist) ----
    unsigned pr0 = 0; float prx = 0.0f, prm = 0.0f;
    unsigned gam_pr = 0;
    if (t < LT - 1){
      if (tid < LDP/2) pr0 = Pd[(size_t)(t+1)*(LDP/2) + tid];
      else {
        int k = tid - LDP/2;
        size_t offx = ((size_t)b*LT + t + 1)*KT + k;
        prx = x[offx]; prm = mask[offx];
      }
      if (tid < HT) gam_pr = Pd[(size_t)(t+1)*(LDP/2) + (tid >> 1)];
    }
    if (tid == 0) s.cnt[nxt] = 0;
    {
      const f16x8* hp = (const f16x8*)s.hsh;
      if (tid < KT){
        float a2 = 0.0f;
        #pragma unroll 8
        for (int c = 0; c < 32; ++c)
          a2 = dot8(s.whist_l[c*128 + tid], hp[c], a2);
        float xh = a2 + s.bhist[tid];
        s.xh[tid] = xh;
        float mv = s.mb[cur][tid], xv = s.xb[cur][tid];
        loss += fabsf(xv - xh) * mv * s.minv[t];
        if (mv == 0.0f){
          int pp = atomicAdd(&s.cnt[cur], 1);
          s.lidx[pp] = tid; s.v3[pp] = xh; s.posk[tid] = pp;
        }
      }
      float acc = 0.0f;
      #pragma unroll 8
      for (int c = 0; c < 32; ++c)
        acc = dot8(Whh_p[c*768 + tid], hp[c], acc);
      s.gh[tid] = acc;
    }
    __syncthreads();

    // ---- C: zh strata (LDS Wfc) + prefetch Wihc sparse columns ----
    const int c0 = s.cnt[cur];
    const int c4 = (c0 + 7) & ~7;
    {
      int st = tid >> 7, j = tid & 127;
      float a = 0.0f;
      for (int i = st; i < c0; i += 6)
        a += s.v3[i] * (float)s.wfc_l[s.lidx[i]*128 + j];
      s.part6[st][j] = a;
    }
    float wpre[16];
    #pragma unroll
    for (int u = 0; u < 16; ++u)
      wpre[u] = (u < c4) ? (float)Wihc[(size_t)s.lidx[u]*768 + tid] : 0.0f;
    __syncthreads();

    // ---- D: z_h, c_h, losses, imputation, v5 (tid<128) ----
    if (tid < KT){
      const int j = tid;
      if (j >= c0 && j < c4) s.v5[j] = 0.0f;
      float z = f16bits(s.pb[cur][ZP0/2 + (j >> 1)], j & 1) + s.bfeat[j]
              + s.part6[0][j] + s.part6[1][j] + s.part6[2][j]
              + s.part6[3][j] + s.part6[4][j] + s.part6[5][j];
      float al = f16bits(s.pb[cur][AL0/2 + (j >> 1)], j & 1);
      float xh = s.xh[j];
      float mv = s.mb[cur][j], xv = s.xb[cur][j];
      float e = (t < rn) ? 1.0f : 0.0f;
      float inv = s.minv[t];
      float ch = al*z + (1.0f - al)*xh;
      loss += (fabsf(xv - z) + fabsf(xv - ch)) * mv * e * inv;
      float cc = mv*xv + (1.0f - mv)*ch;
      out[((size_t)b*LT + t)*KT + j] = cc * e;
      if (mv == 0.0f) s.v5[s.posk[j]] = ch;
    }
    __syncthreads();

    // ---- E: sparse M5 -> gi (prefetched head + unrolled tail) ----
    {
      float g = f16bits(s.pb[cur][GI0/2 + (tid >> 1)], tid & 1);
      #pragma unroll
      for (int u = 0; u < 16; ++u)
        if (u < c4) g += s.v5[u] * wpre[u];
      for (int i = 16; i < c4; i += 8){
        #pragma unroll
        for (int u = 0; u < 8; ++u)
          g += s.v5[i + u] * (float)Wihc[(size_t)s.lidx[i + u]*768 + tid];
      }
      s.gi[tid] = g;
    }
    __syncthreads();

    // ---- F: gates + h update (registers) + hs(t+1)/hsh publish ;
    //         stage prefetched buffers ----
    if (tid < HT){
      const int j = tid;
      float ir = s.gi[j], iz = s.gi[HT + j], ig = s.gi[2*HT + j];
      float hr = s.gh[j] + s.bhh[j];
      float hz = s.gh[HT + j] + s.bhh[HT + j];
      float hg = s.gh[2*HT + j] + s.bhh[2*HT + j];
      float r = sigf(ir + hr);
      float zg = sigf(iz + hz);
      float n = tanh_fast(ig + r*hg);
      float hn = (1.0f - zg)*n + zg*hs_r;
      if (t < rn) h_reg = hn;
      if (t < LT - 1){
        hs_r = h_reg * f16bits(gam_pr, j & 1);   // gamma_h(t+1), GH0 region
        s.hsh[j] = (_Float16)hs_r;
      }
    }
    if (t < LT - 1){
      if (tid < LDP/2) s.pb[nxt][tid] = pr0;
      else {
        int k = tid - LDP/2;
        s.xb[nxt][k] = prx; s.mb[nxt][k] = prm;
      }
    }
    __syncthreads();
  }

  // ---- loss reduction ----
  #pragma unroll
  for (int off = 32; off; off >>= 1) loss += __shfl_down(loss, off);
  if ((tid & 63) == 0) s.red[tid >> 6] = loss;
  __syncthreads();
  if (tid == 0){
    float tot = 0.0f;
    #pragma unroll
    for (int w = 0; w < NT/64; ++w) tot += s.red[w];
    atomicAdd(&out[LOSS_IDX], tot);
  }

  // ---- prediction ----
  if (tid < HT) s.gh[tid] = h_reg * s.wout[tid];
  __syncthreads();
  for (int st2 = 128; st2 > 0; st2 >>= 1){
    if (tid < st2) s.gh[tid] += s.gh[tid + st2];
    __syncthreads();
  }
  if (tid == 0) out[PRED_IDX + b] = sigf(s.gh[0] + b_out[0]);
}

extern "C" void kernel_launch(void* const* d_in, const int* in_sizes, int n_in,
                              void* d_out, int out_size, void* d_ws, size_t ws_size,
                              hipStream_t stream){
  const float* x      = (const float*)d_in[0];
  const float* mask   = (const float*)d_in[1];
  const float* ts     = (const float*)d_in[2];
  const float* W_gh   = (const float*)d_in[3];
  const float* b_gh   = (const float*)d_in[4];
  const float* W_gx   = (const float*)d_in[5];
  const float* b_gx   = (const float*)d_in[6];
  const float* W_hist = (const float*)d_in[7];
  const float* b_hist = (const float*)d_in[8];
  const float* W_feat = (const float*)d_in[9];
  const float* b_feat = (const float*)d_in[10];
  const float* W_comb = (const float*)d_in[11];
  const float* b_comb = (const float*)d_in[12];
  const float* W_ih   = (const float*)d_in[13];
  const float* W_hh   = (const float*)d_in[14];
  const float* b_ih   = (const float*)d_in[15];
  const float* b_hh   = (const float*)d_in[16];
  const float* W_out  = (const float*)d_in[17];
  const float* b_out  = (const float*)d_in[18];
  const int*   rn     = (const int*)d_in[19];
  float* out = (float*)d_out;
  char* ws = (char*)d_ws;

  size_t off = 0;
  auto alloc = [&](size_t bytes) -> char* {
    char* p = ws + off;
    off += (bytes + 255) & ~(size_t)255;
    return p;
  };
  _Float16* P      = (_Float16*)alloc((size_t)BT*LT*LDP*2);   // 167.8 MB
  _Float16* deltas = (_Float16*)alloc((size_t)BT*LT*KT*2);    // 16.8 MB
  _Float16* Agx    = (_Float16*)alloc((size_t)BT*LT*2*KT*2);  // 33.6 MB
  _Float16* U      = (_Float16*)alloc((size_t)BT*LT*2*KT*2);  // 33.6 MB
  _Float16* WghF   = (_Float16*)alloc(HT*KT*2);
  _Float16* WcombF = (_Float16*)alloc(KT*2*KT*2);
  _Float16* WihF   = (_Float16*)alloc(3*HT*2*KT*2);
  _Float16* WfeatF = (_Float16*)alloc(KT*KT*2);
  _Float16* Whh_p  = (_Float16*)alloc(3*HT*HT*2);
  _Float16* Whist_p= (_Float16*)alloc(KT*HT*2);
  _Float16* Wfc    = (_Float16*)alloc(KT*KT*2);
  _Float16* Wihc   = (_Float16*)alloc(KT*3*HT*2);
  float* msumInv   = (float*)alloc(LT*4);

  auto grid1 = [](int n){ return dim3((n + 255)/256); };
  pack_cast<<<grid1(HT*KT), 256, 0, stream>>>(W_gh, WghF, HT, KT, 0, HT*KT);
  pack_cast<<<grid1(KT*2*KT), 256, 0, stream>>>(W_comb, WcombF, KT, 2*KT, 0, KT*2*KT);
  pack_cast<<<grid1(3*HT*2*KT), 256, 0, stream>>>(W_ih, WihF, 3*HT, 2*KT, 0, 3*HT*2*KT);
  pack_cast<<<grid1(KT*KT), 256, 0, stream>>>(W_feat, WfeatF, KT, KT, 1, KT*KT);
  pack_rowchunks<<<grid1(3*HT*(HT/8)), 256, 0, stream>>>(W_hh, Whh_p, 3*HT, HT, 3*HT*(HT/8));
  pack_rowchunks<<<grid1(KT*(HT/8)), 256, 0, stream>>>(W_hist, Whist_p, KT, HT, KT*(HT/8));
  pack_col<<<grid1(KT*KT), 256, 0, stream>>>(W_feat, Wfc, KT, KT, KT, 1, KT*KT);
  pack_col<<<grid1(768*KT), 256, 0, stream>>>(W_ih, Wihc, 3*HT, KT, 2*KT, 0, 3*HT*KT);

  scan_kernel<<<dim3(BT), dim3(KT), 0, stream>>>(x, mask, ts, W_gx, b_gx, rn, deltas, Agx, U);
  msum_kernel<<<dim3(LT), dim3(256), 0, stream>>>(mask, msumInv);

  const int MR = BT*LT;
  gemm_f16<<<dim3(MR/64, HT/64), 256, 0, stream>>>(deltas, KT, KT, WghF, KT, P, GH0, b_gh, 2);
  gemm_f16<<<dim3(MR/64, KT/64), 256, 0, stream>>>(Agx, 2*KT, 2*KT, WcombF, 2*KT, P, AL0, b_comb, 1);
  gemm_f16<<<dim3(MR/64, 3*HT/64), 256, 0, stream>>>(U, 2*KT, 2*KT, WihF, 2*KT, P, GI0, b_ih, 1);
  gemm_f16<<<dim3(MR/64, KT/64), 256, 0, stream>>>(U, 2*KT, KT, WfeatF, KT, P, ZP0, (const float*)nullptr, 0);

  hipMemsetAsync((void*)(out + LOSS_IDX), 0, sizeof(float), stream);

  rits_seq<<<dim3(BT), dim3(NT), 0, stream>>>(x, mask, rn, msumInv, P,
      (const f16x8*)Whh_p, (const f16x8*)Whist_p, Wfc, Wihc,
      b_hist, b_feat, b_hh, W_out, b_out, out);
}